// Round 2
// baseline (1913.634 us; speedup 1.0000x reference)
//
#include <hip/hip_runtime.h>
#include <hip/hip_bf16.h>
#include <stdint.h>

// Problem constants
constexpr int kB = 8;
constexpr int kN = 128;
constexpr int kC = 256;
// scale = 1/sqrt(C) = 1/16
#define ATTN_SCALE 0.0625f

// acc += dot(8 fp32 in two float4, w[0..7])
__device__ __forceinline__ void dot8f(float& acc, float4 u0, float4 u1, const float* w) {
    acc += u0.x * w[0];
    acc += u0.y * w[1];
    acc += u0.z * w[2];
    acc += u0.w * w[3];
    acc += u1.x * w[4];
    acc += u1.y * w[5];
    acc += u1.z * w[6];
    acc += u1.w * w[7];
}

// ---------------------------------------------------------------------------
// Kernel 1: q = mol@Wq+bq, k = prot@Wk+bk, v = mol@Wv+bv  (fp32 to workspace)
// grid: B*N blocks, 256 threads (thread = output channel)
// ---------------------------------------------------------------------------
__global__ __launch_bounds__(256) void qkv_kernel(
    const float* __restrict__ mol_annot,
    const float* __restrict__ prot_annot,
    const float* __restrict__ Wq, const float* __restrict__ bq,
    const float* __restrict__ Wk, const float* __restrict__ bk,
    const float* __restrict__ Wv, const float* __restrict__ bv,
    float* __restrict__ qf, float* __restrict__ kf, float* __restrict__ vf)
{
    const int row = blockIdx.x;   // b*N + m
    const int t   = threadIdx.x;  // channel

    __shared__ float sm[kC];
    __shared__ float sp[kC];
    sm[t] = mol_annot[row * kC + t];
    sp[t] = prot_annot[row * kC + t];
    __syncthreads();

    float aq = bq[t];
    float ak = bk[t];
    float av = bv[t];
    for (int c = 0; c < kC; ++c) {
        const float m = sm[c];
        const float p = sp[c];
        aq += m * Wq[c * kC + t];
        ak += p * Wk[c * kC + t];
        av += m * Wv[c * kC + t];
    }
    qf[row * kC + t] = aq;
    kf[row * kC + t] = ak;
    vf[row * kC + t] = av;
}

// ---------------------------------------------------------------------------
// Kernel 2: fused edge GEMMs + gate + Woed GEMM + online softmax + node GEMM
// grid: B*N blocks (one per (b,m)), 256 threads (thread = channel)
// ---------------------------------------------------------------------------
__global__ __launch_bounds__(256) void main_kernel(
    const float* __restrict__ mol_adj,
    const float* __restrict__ prot_adj,
    const float* __restrict__ Wka, const float* __restrict__ bka,
    const float* __restrict__ Wva, const float* __restrict__ bva,
    const float* __restrict__ Wond, const float* __restrict__ bond,
    const float* __restrict__ Woed, const float* __restrict__ boed,
    const float* __restrict__ qf, const float* __restrict__ kf, const float* __restrict__ vf,
    float* __restrict__ out_node,   // [B,N,C]
    float* __restrict__ out_edge)   // [B,N,N,C]
{
    const int bm = blockIdx.x;     // b*N + m
    const int b  = bm >> 7;        // N = 128
    const int t  = threadIdx.x;    // channel 0..255

    __shared__ __align__(16) float s_at[8][kC];   // attn tile (fp32, for Woed GEMM)
    __shared__ float s_node[kC];

    const float qv = qf[(size_t)bm * kC + t];
    const float bva_t  = bva[t];
    const float bka_t  = bka[t];
    const float boed_t = boed[t];

    const float* madj_base = mol_adj  + (size_t)bm * kN * kC;
    const float* padj_base = prot_adj + (size_t)bm * kN * kC;

    // per-thread (= per-channel) online softmax state
    float run_m = -1.0e30f;
    float run_s = 0.0f;
    float run_a = 0.0f;

    for (int n0 = 0; n0 < kN; n0 += 8) {
        // ---- edge GEMMs: me = mol_adj@Wva+bva, pe = prot_adj@Wka+bka  (8 rows)
        // row j occupies 256 floats = 64 float4, starting at float4 index j*64
        const float4* am0 = reinterpret_cast<const float4*>(madj_base + (size_t)n0 * kC);
        const float4* ap0 = reinterpret_cast<const float4*>(padj_base + (size_t)n0 * kC);

        float me[8], pe[8];
        #pragma unroll
        for (int j = 0; j < 8; ++j) { me[j] = bva_t; pe[j] = bka_t; }

        for (int c8 = 0; c8 < 32; ++c8) {
            float wv[8], wk[8];
            #pragma unroll
            for (int i = 0; i < 8; ++i) {
                wv[i] = Wva[(c8 * 8 + i) * kC + t];
                wk[i] = Wka[(c8 * 8 + i) * kC + t];
            }
            #pragma unroll
            for (int j = 0; j < 8; ++j) {
                dot8f(me[j], am0[j * 64 + c8 * 2], am0[j * 64 + c8 * 2 + 1], wv);
                dot8f(pe[j], ap0[j * 64 + c8 * 2], ap0[j * 64 + c8 * 2 + 1], wk);
            }
        }

        // ---- gate: attn = q*k*scale * (pe+1) * me ; stage tile for Woed
        float at[8];
        #pragma unroll
        for (int j = 0; j < 8; ++j) {
            const int n = n0 + j;
            const float kvv = kf[((size_t)b * kN + n) * kC + t];
            const float a = qv * kvv * ATTN_SCALE * (pe[j] + 1.0f) * me[j];
            at[j] = a;
            s_at[j][t] = a;
        }
        __syncthreads();

        // ---- edge output GEMM: oed = attn @ Woed + boed
        float oed[8];
        #pragma unroll
        for (int j = 0; j < 8; ++j) oed[j] = boed_t;

        const float4* sat4 = reinterpret_cast<const float4*>(&s_at[0][0]);
        for (int c8 = 0; c8 < 32; ++c8) {
            float wo[8];
            #pragma unroll
            for (int i = 0; i < 8; ++i) {
                wo[i] = Woed[(c8 * 8 + i) * kC + t];
            }
            #pragma unroll
            for (int j = 0; j < 8; ++j) {
                dot8f(oed[j], sat4[j * 64 + c8 * 2], sat4[j * 64 + c8 * 2 + 1], wo);
            }
        }

        #pragma unroll
        for (int j = 0; j < 8; ++j) {
            out_edge[((size_t)bm * kN + n0 + j) * kC + t] = oed[j];
        }

        // ---- online softmax + weighted-v accumulation (per-channel, fp32)
        #pragma unroll
        for (int j = 0; j < 8; ++j) {
            const int n = n0 + j;
            const float vv = vf[((size_t)b * kN + n) * kC + t];
            const float m2   = fmaxf(run_m, at[j]);
            const float corr = __expf(run_m - m2);
            const float e    = __expf(at[j] - m2);
            run_s = run_s * corr + e;
            run_a = run_a * corr + e * vv;
            run_m = m2;
        }

        __syncthreads();  // s_at reads done before next tile overwrites
    }

    // ---- node output: (a*v).sum / denom, then @ Wond + bond
    s_node[t] = run_a / run_s;
    __syncthreads();

    float acc = bond[t];
    const float4* sn4 = reinterpret_cast<const float4*>(s_node);
    for (int c4 = 0; c4 < 64; ++c4) {
        const float4 nv = sn4[c4];
        acc += nv.x * Wond[(c4 * 4 + 0) * kC + t];
        acc += nv.y * Wond[(c4 * 4 + 1) * kC + t];
        acc += nv.z * Wond[(c4 * 4 + 2) * kC + t];
        acc += nv.w * Wond[(c4 * 4 + 3) * kC + t];
    }
    out_node[(size_t)bm * kC + t] = acc;
}

// ---------------------------------------------------------------------------
extern "C" void kernel_launch(void* const* d_in, const int* in_sizes, int n_in,
                              void* d_out, int out_size, void* d_ws, size_t ws_size,
                              hipStream_t stream)
{
    const float* mol_annot  = (const float*)d_in[0];
    const float* prot_annot = (const float*)d_in[1];
    const float* mol_adj    = (const float*)d_in[2];
    const float* prot_adj   = (const float*)d_in[3];
    const float* Wq  = (const float*)d_in[4];
    const float* bq  = (const float*)d_in[5];
    const float* Wk  = (const float*)d_in[6];
    const float* bk  = (const float*)d_in[7];
    const float* Wv  = (const float*)d_in[8];
    const float* bv  = (const float*)d_in[9];
    const float* Wka = (const float*)d_in[10];
    const float* bka = (const float*)d_in[11];
    const float* Wva = (const float*)d_in[12];
    const float* bva = (const float*)d_in[13];
    const float* Wond = (const float*)d_in[14];
    const float* bond = (const float*)d_in[15];
    const float* Woed = (const float*)d_in[16];
    const float* boed = (const float*)d_in[17];

    // workspace: q,k,v as fp32 (3 MB)
    float* qf = (float*)d_ws;
    float* kf = qf + (size_t)kB * kN * kC;
    float* vf = kf + (size_t)kB * kN * kC;

    // output layout (flat concat, fp32):
    //   out0 mol_annot_out [B,N,C]    @ 0
    //   out1 prot_annot    [B,N,C]    @ 262144
    //   out2 mol_adj_out   [B,N,N,C]  @ 524288
    //   out3 prot_adj      [B,N,N,C]  @ 34078720
    float* out  = (float*)d_out;
    float* out0 = out;
    float* out1 = out + (size_t)kB * kN * kC;
    float* out2 = out + (size_t)2 * kB * kN * kC;
    float* out3 = out2 + (size_t)kB * kN * kN * kC;

    // passthroughs
    hipMemcpyAsync(out1, prot_annot, (size_t)kB * kN * kC * sizeof(float),
                   hipMemcpyDeviceToDevice, stream);
    hipMemcpyAsync(out3, prot_adj, (size_t)kB * kN * kN * kC * sizeof(float),
                   hipMemcpyDeviceToDevice, stream);

    qkv_kernel<<<dim3(kB * kN), dim3(256), 0, stream>>>(
        mol_annot, prot_annot, Wq, bq, Wk, bk, Wv, bv, qf, kf, vf);

    main_kernel<<<dim3(kB * kN), dim3(256), 0, stream>>>(
        mol_adj, prot_adj, Wka, bka, Wva, bva, Wond, bond, Woed, boed,
        qf, kf, vf, out0, out2);
}